// Round 1
// baseline (334.058 us; speedup 1.0000x reference)
//
#include <hip/hip_runtime.h>
#include <hip/hip_bf16.h>

#define N_SITES 200000
#define CIN 256
#define CMID 64
#define KVOL 9

using bf16x8 = __attribute__((ext_vector_type(8))) short;
using f32x4  = __attribute__((ext_vector_type(4))) float;

__device__ __forceinline__ short f2bf(float f) {
    union { float f; unsigned u; } v; v.f = f;
    unsigned r = v.u + 0x7fffu + ((v.u >> 16) & 1u);   // RNE
    return (short)(r >> 16);
}

__device__ __forceinline__ f32x4 mfma16(bf16x8 a, bf16x8 b, f32x4 c) {
    return __builtin_amdgcn_mfma_f32_16x16x32_bf16(a, b, c, 0, 0, 0);
}

// ---------------- K1: x1 = relu(feat @ W1)  [N,256]x[256,64] -> bf16 [N,64]
__global__ __launch_bounds__(256) void k1_conv1(const float* __restrict__ feat,
                                                const float* __restrict__ W1,
                                                short* __restrict__ x1) {
    __shared__ short w1t[64][264];   // W1^T, padded: stride 528B = 132 dw == 4 mod 32
    const int t = threadIdx.x;
    // fill W1^T (16384 elems), vectorized: 16 iters x (1 dwordx4 + 4 cvt + 4 ds_write)
    #pragma unroll
    for (int i = 0; i < 16; ++i) {
        int idx = i * 1024 + t * 4;        // 4 consecutive n, same k
        int k = idx >> 6, n = idx & 63;
        f32x4 v = *(const f32x4*)&W1[idx];
        #pragma unroll
        for (int j = 0; j < 4; ++j) w1t[n + j][k] = f2bf(v[j]);
    }
    __syncthreads();

    const int lane = t & 63, w = t >> 6;
    const int row0 = blockIdx.x * 64 + w * 16;
    const int arow = row0 + (lane & 15);
    const float* ap = feat + (size_t)arow * CIN + (lane >> 4) * 8;

    f32x4 acc[4] = {};
    #pragma unroll
    for (int ks = 0; ks < 8; ++ks) {
        const f32x4* p = (const f32x4*)(ap + ks * 32);
        f32x4 a0 = p[0], a1 = p[1];
        bf16x8 af;
        #pragma unroll
        for (int j = 0; j < 4; ++j) { af[j] = f2bf(a0[j]); af[4 + j] = f2bf(a1[j]); }
        #pragma unroll
        for (int ct = 0; ct < 4; ++ct) {
            bf16x8 bf = *(const bf16x8*)&w1t[ct * 16 + (lane & 15)][ks * 32 + (lane >> 4) * 8];
            acc[ct] = mfma16(af, bf, acc[ct]);
        }
    }
    const int r0 = row0 + (lane >> 4) * 4;
    #pragma unroll
    for (int ct = 0; ct < 4; ++ct)
        #pragma unroll
        for (int j = 0; j < 4; ++j) {
            float v = acc[ct][j];
            x1[(size_t)(r0 + j) * CMID + ct * 16 + (lane & 15)] = f2bf(v > 0.f ? v : 0.f);
        }
}

// ---------------- K2: x2 = relu(sum_k gather_k(x1) @ W2[k]) -> bf16 [N,64]
__global__ __launch_bounds__(256) void k2_conv2(const short* __restrict__ x1,
                                                const float* __restrict__ W2,
                                                const int* __restrict__ nbr,
                                                short* __restrict__ x2) {
    __shared__ short w2t[64][72];    // W2[k]^T, stride 144B = 36 dw == 4 mod 32
    const int t = threadIdx.x;
    const int lane = t & 63, w = t >> 6;
    const int row0 = blockIdx.x * 64 + w * 16;
    const int site = row0 + (lane & 15);

    f32x4 acc[4] = {};
    for (int kk = 0; kk < KVOL; ++kk) {
        __syncthreads();             // protect previous iteration's reads
        #pragma unroll
        for (int i = 0; i < 4; ++i) {
            int idx = i * 1024 + t * 4;         // 4 consecutive cout, same cin
            int cin = idx >> 6, cout = idx & 63;
            f32x4 v = *(const f32x4*)&W2[kk * 4096 + idx];
            #pragma unroll
            for (int j = 0; j < 4; ++j) w2t[cout + j][cin] = f2bf(v[j]);
        }
        __syncthreads();

        const int idxn = nbr[site * 9 + kk];
        const short* gp = x1 + (size_t)(idxn < 0 ? 0 : idxn) * CMID + (lane >> 4) * 8;
        #pragma unroll
        for (int ks = 0; ks < 2; ++ks) {
            bf16x8 af = {};
            if (idxn >= 0) af = *(const bf16x8*)(gp + ks * 32);   // the gather IS the A-frag
            #pragma unroll
            for (int ct = 0; ct < 4; ++ct) {
                bf16x8 bf = *(const bf16x8*)&w2t[ct * 16 + (lane & 15)][ks * 32 + (lane >> 4) * 8];
                acc[ct] = mfma16(af, bf, acc[ct]);
            }
        }
    }
    const int r0 = row0 + (lane >> 4) * 4;
    #pragma unroll
    for (int ct = 0; ct < 4; ++ct)
        #pragma unroll
        for (int j = 0; j < 4; ++j) {
            float v = acc[ct][j];
            x2[(size_t)(r0 + j) * CMID + ct * 16 + (lane & 15)] = f2bf(v > 0.f ? v : 0.f);
        }
}

// ---------------- K3: out = relu(x2 @ W3 + feat)  [N,64]x[64,256] -> f32 [N,256]
__global__ __launch_bounds__(256) void k3_conv3(const short* __restrict__ x2,
                                                const float* __restrict__ W3,
                                                const float* __restrict__ feat,
                                                float* __restrict__ out) {
    __shared__ short w3t[256][72];   // W3^T
    const int t = threadIdx.x;
    #pragma unroll
    for (int i = 0; i < 16; ++i) {
        int idx = i * 1024 + t * 4;         // 4 consecutive cout, same cmid
        int cm = idx >> 8, co = idx & 255;
        f32x4 v = *(const f32x4*)&W3[idx];
        #pragma unroll
        for (int j = 0; j < 4; ++j) w3t[co + j][cm] = f2bf(v[j]);
    }
    __syncthreads();

    const int lane = t & 63, w = t >> 6;
    const int row0 = blockIdx.x * 64 + w * 16;
    const short* ap = x2 + (size_t)(row0 + (lane & 15)) * CMID + (lane >> 4) * 8;

    f32x4 acc[16] = {};
    #pragma unroll
    for (int ks = 0; ks < 2; ++ks) {
        bf16x8 af = *(const bf16x8*)(ap + ks * 32);
        #pragma unroll
        for (int ct = 0; ct < 16; ++ct) {
            bf16x8 bf = *(const bf16x8*)&w3t[ct * 16 + (lane & 15)][ks * 32 + (lane >> 4) * 8];
            acc[ct] = mfma16(af, bf, acc[ct]);
        }
    }
    const int r0 = row0 + (lane >> 4) * 4;
    #pragma unroll
    for (int ct = 0; ct < 16; ++ct)
        #pragma unroll
        for (int j = 0; j < 4; ++j) {
            size_t o = (size_t)(r0 + j) * CIN + ct * 16 + (lane & 15);
            float v = acc[ct][j] + feat[o];
            out[o] = v > 0.f ? v : 0.f;
        }
}

extern "C" void kernel_launch(void* const* d_in, const int* in_sizes, int n_in,
                              void* d_out, int out_size, void* d_ws, size_t ws_size,
                              hipStream_t stream) {
    const float* feat = (const float*)d_in[0];
    const float* W1   = (const float*)d_in[1];
    const float* W2   = (const float*)d_in[2];
    const float* W3   = (const float*)d_in[3];
    const int*   nbr  = (const int*)d_in[4];

    short* x1 = (short*)d_ws;                           // [N,64] bf16, 25.6 MB
    short* x2 = x1 + (size_t)N_SITES * CMID;            // [N,64] bf16, 25.6 MB
    float* out = (float*)d_out;

    const int blocks = N_SITES / 64;                    // 3125
    hipLaunchKernelGGL(k1_conv1, dim3(blocks), dim3(256), 0, stream, feat, W1, x1);
    hipLaunchKernelGGL(k2_conv2, dim3(blocks), dim3(256), 0, stream, x1, W2, nbr, x2);
    hipLaunchKernelGGL(k3_conv3, dim3(blocks), dim3(256), 0, stream, x2, W3, feat, out);
}

// Round 2
// 181.435 us; speedup vs baseline: 1.8412x; 1.8412x over previous
//
#include <hip/hip_runtime.h>
#include <hip/hip_bf16.h>

#define N_SITES 200000
#define CIN 256
#define CMID 64
#define KVOL 9

using bf16x8 = __attribute__((ext_vector_type(8))) short;
using f32x4  = __attribute__((ext_vector_type(4))) float;

__device__ __forceinline__ short f2bf(float f) {
    union { float f; unsigned u; } v; v.f = f;
    unsigned r = v.u + 0x7fffu + ((v.u >> 16) & 1u);   // RNE
    return (short)(r >> 16);
}

__device__ __forceinline__ f32x4 mfma16(bf16x8 a, bf16x8 b, f32x4 c) {
    return __builtin_amdgcn_mfma_f32_16x16x32_bf16(a, b, c, 0, 0, 0);
}

// ---------------- K1: x1 = relu(feat @ W1)  [N,256]x[256,64] -> bf16 [N,64]
__global__ __launch_bounds__(256) void k1_conv1(const float* __restrict__ feat,
                                                const float* __restrict__ W1,
                                                short* __restrict__ x1) {
    __shared__ short w1t[64][264];   // W1^T  (stride 528B: 16B-aligned, reads balanced)
    __shared__ short o1[64][72];     // bf16 out staging
    const int t = threadIdx.x;
    const int lane = t & 63, w = t >> 6;
    const int r = lane & 15, g = lane >> 4;

    // stage W1^T: coalesced loads along n, b64 writes along k
    #pragma unroll
    for (int q = 0; q < 16; ++q) {
        int k0 = 4 * w + 16 * q;
        float v0 = W1[(k0 + 0) * 64 + lane];
        float v1 = W1[(k0 + 1) * 64 + lane];
        float v2 = W1[(k0 + 2) * 64 + lane];
        float v3 = W1[(k0 + 3) * 64 + lane];
        short4 s = make_short4(f2bf(v0), f2bf(v1), f2bf(v2), f2bf(v3));
        *(short4*)&w1t[lane][k0] = s;
    }
    __syncthreads();

    const int row0 = blockIdx.x * 64 + w * 16;
    const float* ap = feat + (size_t)(row0 + r) * CIN + g * 8;

    f32x4 acc[4] = {};
    #pragma unroll
    for (int ks = 0; ks < 8; ++ks) {
        f32x4 a0 = *(const f32x4*)(ap + ks * 32);
        f32x4 a1 = *(const f32x4*)(ap + ks * 32 + 4);
        bf16x8 af;
        #pragma unroll
        for (int j = 0; j < 4; ++j) { af[j] = f2bf(a0[j]); af[4 + j] = f2bf(a1[j]); }
        #pragma unroll
        for (int ct = 0; ct < 4; ++ct) {
            bf16x8 bf = *(const bf16x8*)&w1t[ct * 16 + r][ks * 32 + g * 8];
            acc[ct] = mfma16(af, bf, acc[ct]);
        }
    }
    // epilogue: stage -> coalesced b128 writes
    #pragma unroll
    for (int ct = 0; ct < 4; ++ct)
        #pragma unroll
        for (int j = 0; j < 4; ++j) {
            float v = acc[ct][j];
            o1[w * 16 + g * 4 + j][ct * 16 + r] = f2bf(v > 0.f ? v : 0.f);
        }
    __syncthreads();
    #pragma unroll
    for (int i = 0; i < 2; ++i) {
        int v = t + 256 * i; int row = v >> 3, c8 = v & 7;
        *(bf16x8*)&x1[(size_t)(blockIdx.x * 64 + row) * CMID + c8 * 8] =
            *(const bf16x8*)&o1[row][c8 * 8];
    }
}

// ---------------- K2: x2 = relu(sum_k gather_k(x1) @ W2[k]) -> bf16 [N,64]
__global__ __launch_bounds__(256) void k2_conv2(const short* __restrict__ x1,
                                                const float* __restrict__ W2,
                                                const int* __restrict__ nbr,
                                                short* __restrict__ x2) {
    __shared__ short w2t[2][64][72];  // double-buffered W2[k]^T
    __shared__ short o2[64][72];
    const int t = threadIdx.x;
    const int lane = t & 63, w = t >> 6;
    const int r = lane & 15, g = lane >> 4;
    const int row0 = blockIdx.x * 64 + w * 16;
    const int site = row0 + r;

    int idx9[9];
    #pragma unroll
    for (int kk = 0; kk < 9; ++kk) idx9[kk] = nbr[site * 9 + kk];

    // stage tile 0
    #pragma unroll
    for (int q = 0; q < 4; ++q) {
        int k0 = 4 * w + 16 * q;
        float v0 = W2[(k0 + 0) * 64 + lane];
        float v1 = W2[(k0 + 1) * 64 + lane];
        float v2 = W2[(k0 + 2) * 64 + lane];
        float v3 = W2[(k0 + 3) * 64 + lane];
        *(short4*)&w2t[0][lane][k0] = make_short4(f2bf(v0), f2bf(v1), f2bf(v2), f2bf(v3));
    }
    // prefetch gather 0
    bf16x8 a0c = {}, a1c = {};
    { int ii = idx9[0];
      if (ii >= 0) { const short* gp = x1 + (size_t)ii * CMID + g * 8;
                     a0c = *(const bf16x8*)gp; a1c = *(const bf16x8*)(gp + 32); } }
    __syncthreads();

    f32x4 acc[4] = {};
    for (int kk = 0; kk < 9; ++kk) {
        const int cur = kk & 1;
        // prefetch next gather (A-frag IS the rulebook gather)
        bf16x8 a0n = {}, a1n = {};
        if (kk < 8) {
            int ii = idx9[kk + 1];
            if (ii >= 0) { const short* gp = x1 + (size_t)ii * CMID + g * 8;
                           a0n = *(const bf16x8*)gp; a1n = *(const bf16x8*)(gp + 32); }
        }
        // load next W2 tile to regs (coalesced)
        float nv[16];
        if (kk < 8) {
            #pragma unroll
            for (int q = 0; q < 4; ++q) {
                int k0 = 4 * w + 16 * q;
                #pragma unroll
                for (int c = 0; c < 4; ++c)
                    nv[q * 4 + c] = W2[(kk + 1) * 4096 + (k0 + c) * 64 + lane];
            }
        }
        // MFMA from current tile
        #pragma unroll
        for (int ct = 0; ct < 4; ++ct) {
            bf16x8 b0 = *(const bf16x8*)&w2t[cur][ct * 16 + r][g * 8];
            bf16x8 b1 = *(const bf16x8*)&w2t[cur][ct * 16 + r][32 + g * 8];
            acc[ct] = mfma16(a0c, b0, acc[ct]);
            acc[ct] = mfma16(a1c, b1, acc[ct]);
        }
        // write next tile into other buffer
        if (kk < 8) {
            #pragma unroll
            for (int q = 0; q < 4; ++q) {
                int k0 = 4 * w + 16 * q;
                *(short4*)&w2t[cur ^ 1][lane][k0] =
                    make_short4(f2bf(nv[q*4+0]), f2bf(nv[q*4+1]), f2bf(nv[q*4+2]), f2bf(nv[q*4+3]));
            }
        }
        __syncthreads();
        a0c = a0n; a1c = a1n;
    }
    // epilogue
    #pragma unroll
    for (int ct = 0; ct < 4; ++ct)
        #pragma unroll
        for (int j = 0; j < 4; ++j) {
            float v = acc[ct][j];
            o2[w * 16 + g * 4 + j][ct * 16 + r] = f2bf(v > 0.f ? v : 0.f);
        }
    __syncthreads();
    #pragma unroll
    for (int i = 0; i < 2; ++i) {
        int v = t + 256 * i; int row = v >> 3, c8 = v & 7;
        *(bf16x8*)&x2[(size_t)(blockIdx.x * 64 + row) * CMID + c8 * 8] =
            *(const bf16x8*)&o2[row][c8 * 8];
    }
}

// ---------------- K3: out = relu(x2 @ W3 + feat)  [N,64]x[64,256] -> f32 [N,256]
__global__ __launch_bounds__(256) void k3_conv3(const short* __restrict__ x2,
                                                const float* __restrict__ W3,
                                                const float* __restrict__ feat,
                                                float* __restrict__ out) {
    __shared__ short w3t[256][72];   // W3^T
    __shared__ float ot[64][36];     // f32 out staging, 32-col chunks
    const int t = threadIdx.x;
    const int lane = t & 63, w = t >> 6;
    const int r = lane & 15, g = lane >> 4;

    // stage W3^T: thread t owns output-column co = t; coalesced loads, b64 writes
    #pragma unroll
    for (int q = 0; q < 16; ++q) {
        int k0 = 4 * q;
        float v0 = W3[(k0 + 0) * 256 + t];
        float v1 = W3[(k0 + 1) * 256 + t];
        float v2 = W3[(k0 + 2) * 256 + t];
        float v3 = W3[(k0 + 3) * 256 + t];
        *(short4*)&w3t[t][k0] = make_short4(f2bf(v0), f2bf(v1), f2bf(v2), f2bf(v3));
    }
    __syncthreads();

    const int row0 = blockIdx.x * 64 + w * 16;
    const short* ap = x2 + (size_t)(row0 + r) * CMID + g * 8;
    bf16x8 a0 = *(const bf16x8*)ap;
    bf16x8 a1 = *(const bf16x8*)(ap + 32);

    f32x4 acc[16];
    #pragma unroll
    for (int ct = 0; ct < 16; ++ct) {
        bf16x8 b0 = *(const bf16x8*)&w3t[ct * 16 + r][g * 8];
        bf16x8 b1 = *(const bf16x8*)&w3t[ct * 16 + r][32 + g * 8];
        f32x4 z = {};
        z = mfma16(a0, b0, z);
        acc[ct] = mfma16(a1, b1, z);
    }

    // epilogue: 8 chunks of 32 cols, LDS-staged, fully coalesced f32x4 RMW
    for (int c = 0; c < 8; ++c) {
        __syncthreads();
        #pragma unroll
        for (int ci = 0; ci < 2; ++ci)
            #pragma unroll
            for (int j = 0; j < 4; ++j)
                ot[w * 16 + g * 4 + j][ci * 16 + r] = acc[c * 2 + ci][j];
        __syncthreads();
        #pragma unroll
        for (int i = 0; i < 2; ++i) {
            int v = t + 256 * i; int row = v >> 3, c4 = v & 7;
            size_t o = (size_t)(blockIdx.x * 64 + row) * CIN + c * 32 + c4 * 4;
            f32x4 f = *(const f32x4*)&feat[o];
            f32x4 a = *(const f32x4*)&ot[row][c4 * 4];
            f32x4 res;
            #pragma unroll
            for (int j = 0; j < 4; ++j) { float x = a[j] + f[j]; res[j] = x > 0.f ? x : 0.f; }
            *(f32x4*)&out[o] = res;
        }
    }
}

extern "C" void kernel_launch(void* const* d_in, const int* in_sizes, int n_in,
                              void* d_out, int out_size, void* d_ws, size_t ws_size,
                              hipStream_t stream) {
    const float* feat = (const float*)d_in[0];
    const float* W1   = (const float*)d_in[1];
    const float* W2   = (const float*)d_in[2];
    const float* W3   = (const float*)d_in[3];
    const int*   nbr  = (const int*)d_in[4];

    short* x1 = (short*)d_ws;                           // [N,64] bf16
    short* x2 = x1 + (size_t)N_SITES * CMID;            // [N,64] bf16
    float* out = (float*)d_out;

    const int blocks = N_SITES / 64;                    // 3125
    hipLaunchKernelGGL(k1_conv1, dim3(blocks), dim3(256), 0, stream, feat, W1, x1);
    hipLaunchKernelGGL(k2_conv2, dim3(blocks), dim3(256), 0, stream, x1, W2, nbr, x2);
    hipLaunchKernelGGL(k3_conv3, dim3(blocks), dim3(256), 0, stream, x2, W3, feat, out);
}

// Round 3
// 164.260 us; speedup vs baseline: 2.0337x; 1.1046x over previous
//
#include <hip/hip_runtime.h>
#include <hip/hip_bf16.h>

#define N_SITES 200000
#define CIN 256
#define CMID 64
#define KVOL 9

using bf16x8 = __attribute__((ext_vector_type(8))) short;
using f32x4  = __attribute__((ext_vector_type(4))) float;

__device__ __forceinline__ short f2bf(float f) {
    union { float f; unsigned u; } v; v.f = f;
    unsigned r = v.u + 0x7fffu + ((v.u >> 16) & 1u);   // RNE
    return (short)(r >> 16);
}

__device__ __forceinline__ f32x4 mfma16(bf16x8 a, bf16x8 b, f32x4 c) {
    return __builtin_amdgcn_mfma_f32_16x16x32_bf16(a, b, c, 0, 0, 0);
}

// ---------------- K1: x1 = relu(feat @ W1)  [N,256]x[256,64] -> bf16 [N,64]
__global__ __launch_bounds__(256) void k1_conv1(const float* __restrict__ feat,
                                                const float* __restrict__ W1,
                                                short* __restrict__ x1) {
    __shared__ short w1t[64][264];   // W1^T
    __shared__ short o1[64][72];     // bf16 out staging
    const int t = threadIdx.x;
    const int lane = t & 63, w = t >> 6;
    const int r = lane & 15, g = lane >> 4;

    #pragma unroll
    for (int q = 0; q < 16; ++q) {
        int k0 = 4 * w + 16 * q;
        float v0 = W1[(k0 + 0) * 64 + lane];
        float v1 = W1[(k0 + 1) * 64 + lane];
        float v2 = W1[(k0 + 2) * 64 + lane];
        float v3 = W1[(k0 + 3) * 64 + lane];
        *(short4*)&w1t[lane][k0] = make_short4(f2bf(v0), f2bf(v1), f2bf(v2), f2bf(v3));
    }
    __syncthreads();

    const int row0 = blockIdx.x * 64 + w * 16;
    const float* ap = feat + (size_t)(row0 + r) * CIN + g * 8;

    f32x4 acc[4] = {};
    #pragma unroll
    for (int ks = 0; ks < 8; ++ks) {
        f32x4 a0 = *(const f32x4*)(ap + ks * 32);
        f32x4 a1 = *(const f32x4*)(ap + ks * 32 + 4);
        bf16x8 af;
        #pragma unroll
        for (int j = 0; j < 4; ++j) { af[j] = f2bf(a0[j]); af[4 + j] = f2bf(a1[j]); }
        #pragma unroll
        for (int ct = 0; ct < 4; ++ct) {
            bf16x8 bf = *(const bf16x8*)&w1t[ct * 16 + r][ks * 32 + g * 8];
            acc[ct] = mfma16(af, bf, acc[ct]);
        }
    }
    #pragma unroll
    for (int ct = 0; ct < 4; ++ct)
        #pragma unroll
        for (int j = 0; j < 4; ++j) {
            float v = acc[ct][j];
            o1[w * 16 + g * 4 + j][ct * 16 + r] = f2bf(v > 0.f ? v : 0.f);
        }
    __syncthreads();
    #pragma unroll
    for (int i = 0; i < 2; ++i) {
        int v = t + 256 * i; int row = v >> 3, c8 = v & 7;
        *(bf16x8*)&x1[(size_t)(blockIdx.x * 64 + row) * CMID + c8 * 8] =
            *(const bf16x8*)&o1[row][c8 * 8];
    }
}

// ---------------- K23: fused conv2 (3x3 gather GEMM) + relu + conv3 + residual + relu
__global__ __launch_bounds__(256) void k23_fused(const short* __restrict__ x1,
                                                 const float* __restrict__ W2,
                                                 const float* __restrict__ W3,
                                                 const int* __restrict__ nbr,
                                                 const float* __restrict__ feat,
                                                 float* __restrict__ out) {
    __shared__ short w2t[2][64][72];  // double-buffered W2[k]^T  (18 KB)
    __shared__ short w3t[256][72];    // W3^T                     (36 KB)
    __shared__ short o2[64][72];      // x2 tile, bf16            (9 KB)
    __shared__ float ot[64][36];      // f32 out staging chunk    (9 KB)
    const int t = threadIdx.x;
    const int lane = t & 63, w = t >> 6;
    const int r = lane & 15, g = lane >> 4;
    const int row0 = blockIdx.x * 64 + w * 16;
    const int site = row0 + r;

    int idx9[9];
    #pragma unroll
    for (int kk = 0; kk < 9; ++kk) idx9[kk] = nbr[site * 9 + kk];

    // stage W3^T (thread t owns output column t)
    #pragma unroll
    for (int q = 0; q < 16; ++q) {
        int k0 = 4 * q;
        float v0 = W3[(k0 + 0) * 256 + t];
        float v1 = W3[(k0 + 1) * 256 + t];
        float v2 = W3[(k0 + 2) * 256 + t];
        float v3 = W3[(k0 + 3) * 256 + t];
        *(short4*)&w3t[t][k0] = make_short4(f2bf(v0), f2bf(v1), f2bf(v2), f2bf(v3));
    }
    // stage W2 tile 0
    #pragma unroll
    for (int q = 0; q < 4; ++q) {
        int k0 = 4 * w + 16 * q;
        float v0 = W2[(k0 + 0) * 64 + lane];
        float v1 = W2[(k0 + 1) * 64 + lane];
        float v2 = W2[(k0 + 2) * 64 + lane];
        float v3 = W2[(k0 + 3) * 64 + lane];
        *(short4*)&w2t[0][lane][k0] = make_short4(f2bf(v0), f2bf(v1), f2bf(v2), f2bf(v3));
    }
    // prefetch gather 0 (the gather IS the A-fragment)
    bf16x8 a0c = {}, a1c = {};
    { int ii = idx9[0];
      if (ii >= 0) { const short* gp = x1 + (size_t)ii * CMID + g * 8;
                     a0c = *(const bf16x8*)gp; a1c = *(const bf16x8*)(gp + 32); } }
    __syncthreads();

    // ---- conv2: 9-offset gather GEMM, double-buffered weights, prefetched gathers
    f32x4 acc2[4] = {};
    for (int kk = 0; kk < 9; ++kk) {
        const int cur = kk & 1;
        bf16x8 a0n = {}, a1n = {};
        if (kk < 8) {
            int ii = idx9[kk + 1];
            if (ii >= 0) { const short* gp = x1 + (size_t)ii * CMID + g * 8;
                           a0n = *(const bf16x8*)gp; a1n = *(const bf16x8*)(gp + 32); }
        }
        float nv[16];
        if (kk < 8) {
            #pragma unroll
            for (int q = 0; q < 4; ++q) {
                int k0 = 4 * w + 16 * q;
                #pragma unroll
                for (int c = 0; c < 4; ++c)
                    nv[q * 4 + c] = W2[(kk + 1) * 4096 + (k0 + c) * 64 + lane];
            }
        }
        #pragma unroll
        for (int ct = 0; ct < 4; ++ct) {
            bf16x8 b0 = *(const bf16x8*)&w2t[cur][ct * 16 + r][g * 8];
            bf16x8 b1 = *(const bf16x8*)&w2t[cur][ct * 16 + r][32 + g * 8];
            acc2[ct] = mfma16(a0c, b0, acc2[ct]);
            acc2[ct] = mfma16(a1c, b1, acc2[ct]);
        }
        if (kk < 8) {
            #pragma unroll
            for (int q = 0; q < 4; ++q) {
                int k0 = 4 * w + 16 * q;
                *(short4*)&w2t[cur ^ 1][lane][k0] =
                    make_short4(f2bf(nv[q*4+0]), f2bf(nv[q*4+1]), f2bf(nv[q*4+2]), f2bf(nv[q*4+3]));
            }
        }
        __syncthreads();
        a0c = a0n; a1c = a1n;
    }

    // ---- x2 tile -> LDS (per-wave region), then read back as conv3 A-fragments
    #pragma unroll
    for (int ct = 0; ct < 4; ++ct)
        #pragma unroll
        for (int j = 0; j < 4; ++j) {
            float v = acc2[ct][j];
            o2[w * 16 + g * 4 + j][ct * 16 + r] = f2bf(v > 0.f ? v : 0.f);
        }
    __syncthreads();

    bf16x8 a0 = *(const bf16x8*)&o2[w * 16 + r][g * 8];
    bf16x8 a1 = *(const bf16x8*)&o2[w * 16 + r][32 + g * 8];

    // ---- conv3: [16 rows x 64] @ [64 x 256]
    f32x4 acc3[16];
    #pragma unroll
    for (int ct = 0; ct < 16; ++ct) {
        bf16x8 b0 = *(const bf16x8*)&w3t[ct * 16 + r][g * 8];
        bf16x8 b1 = *(const bf16x8*)&w3t[ct * 16 + r][32 + g * 8];
        f32x4 z = {};
        z = mfma16(a0, b0, z);
        acc3[ct] = mfma16(a1, b1, z);
    }

    // ---- epilogue: 8 chunks of 32 cols, LDS-staged, coalesced nt RMW
    for (int c = 0; c < 8; ++c) {
        __syncthreads();
        #pragma unroll
        for (int ci = 0; ci < 2; ++ci)
            #pragma unroll
            for (int j = 0; j < 4; ++j)
                ot[w * 16 + g * 4 + j][ci * 16 + r] = acc3[c * 2 + ci][j];
        __syncthreads();
        #pragma unroll
        for (int i = 0; i < 2; ++i) {
            int v = t + 256 * i; int row = v >> 3, c4 = v & 7;
            size_t o = (size_t)(blockIdx.x * 64 + row) * CIN + c * 32 + c4 * 4;
            f32x4 f = __builtin_nontemporal_load((const f32x4*)&feat[o]);
            f32x4 a = *(const f32x4*)&ot[row][c4 * 4];
            f32x4 res;
            #pragma unroll
            for (int j = 0; j < 4; ++j) { float x = a[j] + f[j]; res[j] = x > 0.f ? x : 0.f; }
            __builtin_nontemporal_store(res, (f32x4*)&out[o]);
        }
    }
}

extern "C" void kernel_launch(void* const* d_in, const int* in_sizes, int n_in,
                              void* d_out, int out_size, void* d_ws, size_t ws_size,
                              hipStream_t stream) {
    const float* feat = (const float*)d_in[0];
    const float* W1   = (const float*)d_in[1];
    const float* W2   = (const float*)d_in[2];
    const float* W3   = (const float*)d_in[3];
    const int*   nbr  = (const int*)d_in[4];

    short* x1 = (short*)d_ws;                           // [N,64] bf16
    float* out = (float*)d_out;

    const int blocks = N_SITES / 64;                    // 3125
    hipLaunchKernelGGL(k1_conv1, dim3(blocks), dim3(256), 0, stream, feat, W1, x1);
    hipLaunchKernelGGL(k23_fused, dim3(blocks), dim3(256), 0, stream,
                       x1, W2, W3, nbr, feat, out);
}